// Round 11
// baseline (703.228 us; speedup 1.0000x reference)
//
#include <hip/hip_runtime.h>
#include <hip/hip_bf16.h>
#include <cstddef>

// EdgeDegreeEmbedding, round 10 = round 9 + wigner compaction pipelined into
// the (latency-bound) MLP kernel.
//  - mlp is stall-bound (~1.5 TB/s used of ~6.3); agg is BW-bound reading
//    wigner rows at 1900 B when only 500 B (cols 0..4 of 19) are needed.
//  - mlp now also compacts its block's wigner rows -> wigC[e][125] (loads
//    issued before GEMM3, stores after F stores: latency hides under GEMM3).
//  - agg reads wigC coalesced: its HBM drops 877 -> 429 MB.
// r9 mlp structure (MB=64/512thr, single-term bf16 W, B-prefetch), 256-thr
// agg, CSR build, fallback: unchanged.

#define MB 64
#define MTHREADS 512
#define DIN 384
#define HDIM 128
#define NOUT 160
#define NKF 25
#define WIG_LD 19
#define WIG_ROW 475

#define WP1OFF 98304     // bytes: W0 pack = 12kt*8nt*1024
#define WP2OFF 131072    // + W1 pack 4*8*1024 = 32768
#define WPBYTES 172032   // + W2 pack 4*10*1024 = 40960

// LDS layout (bytes)
#define XS_B   784       // Xb row stride: (384+8) bf16
#define FS_B   528       // Hf row stride: 132 f32
#define HS_B   272       // Hb row stride: (128+8) bf16
#define REG0   0         // Xb (64*784=50176) / Hf (64*528=33792)
#define REG1   50176     // Hb (64*272=17408)
#define METAS  67584     // sS[64]
#define METAR  67840     // rS[64]
#define LDSSZ  68096

typedef __attribute__((ext_vector_type(8))) short short8;
typedef __attribute__((ext_vector_type(4))) float f32x4;

struct BF4 { __hip_bfloat162 a, b; };   // 8 B = 4 bf16

__device__ __forceinline__ unsigned short f2bf(float f)
{
    union { float f; unsigned u; } x; x.f = f;
    unsigned r = x.u + 0x7fffu + ((x.u >> 16) & 1u);
    return (unsigned short)(r >> 16);
}

// ---------------------------------------------------------------- W repack
// B-frag block (1024 B) = one (kt, nt): 64 lanes x 8 bf16.
// lane l holds B[kt*32 + 8*(l>>4)+i][nt*16 + (l&15)]. Single term (RN bf16).
__global__ void repack_w(const float* __restrict__ W0, const float* __restrict__ W1,
                         const float* __restrict__ W2, unsigned short* __restrict__ Wp)
{
    const int id = blockIdx.x * 256 + threadIdx.x;
    const float* W; int k, n, NT, N; size_t base;  // base in ushort units
    if (id < 49152)      { W = W0; k = id >> 7;  n = id & 127;  NT = 8;  N = 128; base = 0; }
    else if (id < 65536) { int r = id - 49152; W = W1; k = r >> 7; n = r & 127; NT = 8; N = 128; base = 49152; }
    else if (id < 86016) { int r = id - 65536; W = W2; k = r / 160; n = r - 160 * k; NT = 10; N = 160; base = 65536; }
    else return;
    const float w = W[(size_t)k * N + n];
    const int kt = k >> 5, kk = k & 31;
    const int l = ((kk >> 3) << 4) | (n & 15);
    const int i = kk & 7;
    const int nt = n >> 4;
    Wp[base + (size_t)(kt * NT + nt) * 512 + l * 8 + i] = f2bf(w);
}

// ---------------------------------------------------------------- GEMM core
// 4 M-tiles (64 rows) per wave, one N-tile nt. Fully unrolled; B[kt+1]
// prefetched into registers before kt's MFMAs (hides L2 latency).
template<int NT, int KT>
__device__ __forceinline__ void gemm_tiles4(const char* __restrict__ ldsA, int astride,
                                            const char* __restrict__ wp,
                                            int nt, int lane, f32x4 acc[4])
{
    const int lr = lane & 15, lk = lane >> 4;
    short8 bcur = *(const short8*)(wp + (size_t)nt * 1024 + lane * 16);
#pragma unroll
    for (int kt = 0; kt < KT; ++kt) {
        short8 bnxt = bcur;
        if (kt + 1 < KT)
            bnxt = *(const short8*)(wp + (size_t)((kt + 1) * NT + nt) * 1024 + lane * 16);
        short8 a[4];
#pragma unroll
        for (int mt = 0; mt < 4; ++mt)
            a[mt] = *(const short8*)(ldsA + (mt * 16 + lr) * astride + kt * 64 + lk * 16);
#pragma unroll
        for (int mt = 0; mt < 4; ++mt)
            acc[mt] = __builtin_amdgcn_mfma_f32_16x16x32_bf16(a[mt], bcur, acc[mt], 0, 0, 0);
        bcur = bnxt;
    }
}

__device__ __forceinline__ void dump_acc4(char* Hf, int nt, int lane, const f32x4 acc[4],
                                          const float bias)
{
    const int lr = lane & 15, lk = lane >> 4;
#pragma unroll
    for (int mt = 0; mt < 4; ++mt)
#pragma unroll
        for (int i = 0; i < 4; ++i)
            *(float*)(Hf + (mt * 16 + lk * 4 + i) * FS_B + (nt * 16 + lr) * 4) = acc[mt][i] + bias;
}

// LN + silu: read f32 (FS_B), write packed bf16 (HS_B). 512 thr, 64 rows,
// 8 threads/row x 16 channels.
__device__ __forceinline__ void ln_silu_bf(const char* Hf, char* Hb,
                                           const float* __restrict__ s,
                                           const float* __restrict__ b, int t)
{
    const int j = t & 7;
    const int r = t >> 3;
    float v[16];
    float sum = 0.f, sq = 0.f;
#pragma unroll
    for (int q4 = 0; q4 < 4; ++q4) {
        const float4 x4 = *(const float4*)(Hf + r * FS_B + (j * 16 + q4 * 4) * 4);
        v[q4 * 4 + 0] = x4.x; v[q4 * 4 + 1] = x4.y;
        v[q4 * 4 + 2] = x4.z; v[q4 * 4 + 3] = x4.w;
    }
#pragma unroll
    for (int q = 0; q < 16; ++q) { sum += v[q]; sq = fmaf(v[q], v[q], sq); }
#pragma unroll
    for (int m = 1; m < 8; m <<= 1) {
        sum += __shfl_xor(sum, m, 64);
        sq  += __shfl_xor(sq,  m, 64);
    }
    const float mu = sum * (1.f / 128.f);
    const float var = sq * (1.f / 128.f) - mu * mu;
    const float rstd = rsqrtf(var + 1e-6f);
#pragma unroll
    for (int q = 0; q < 16; q += 2) {
        const int c0 = j * 16 + q;
        float y0 = (v[q] - mu) * rstd * s[c0] + b[c0];
        float y1 = (v[q + 1] - mu) * rstd * s[c0 + 1] + b[c0 + 1];
        y0 = y0 / (1.f + __expf(-y0));
        y1 = y1 / (1.f + __expf(-y1));
        *(__hip_bfloat162*)(Hb + r * HS_B + c0 * 2) =
            __float22bfloat162_rn(make_float2(y0, y1));
    }
}

// ---------------------------------------------------------------- MLP (MFMA)
__global__ __launch_bounds__(MTHREADS, 2)
void mlp_mfma(
    const int* __restrict__ species,
    const float* __restrict__ edge_embeds,
    const int* __restrict__ senders,
    const int* __restrict__ receivers,
    const float* __restrict__ embed_table,
    const char* __restrict__ Wp,
    const float* __restrict__ b0, const float* __restrict__ ln0s, const float* __restrict__ ln0b,
    const float* __restrict__ b1, const float* __restrict__ ln1s, const float* __restrict__ ln1b,
    const float* __restrict__ b2,
    const float* __restrict__ wigner,
    float* __restrict__ wigC,
    float* __restrict__ F,
    int n_edges)
{
    __shared__ alignas(16) char lds[LDSSZ];
    int* sS = (int*)(lds + METAS);
    int* rS = (int*)(lds + METAR);

    const int t = threadIdx.x;
    const int e0 = blockIdx.x * MB;
    const int w = t >> 6;
    const int lane = t & 63;
    const int lr = lane & 15, lk = lane >> 4;

    if (t < MB) {
        const int e = e0 + t;
        int s = 0, r = 0;
        if (e < n_edges) { s = senders[e]; r = receivers[e]; }
        sS[t] = species[s];
        rS[t] = species[r];
    }
    __syncthreads();

    // ---- stage X -> bf16 LDS (8 threads/row, 4-col chunks, stride 32) ----
    {
        const int row = t >> 3;            // 0..63
        const int e = e0 + row;
        const bool ev = e < n_edges;
        const int ss = sS[row], rr = rS[row];
        char* xrow = lds + REG0 + row * XS_B;
        const int c0 = (t & 7) * 4;
#pragma unroll
        for (int jj = 0; jj < 12; ++jj) {
            const int col = c0 + 32 * jj;   // jj<4: edge; jj<8: sender; else recv
            float4 v = make_float4(0.f, 0.f, 0.f, 0.f);
            if (ev) {
                if (jj < 4)
                    v = *(const float4*)(edge_embeds + (size_t)e * 128 + col);
                else if (jj < 8)
                    v = *(const float4*)(embed_table + (size_t)ss * 256 + (col - 128));
                else
                    v = *(const float4*)(embed_table + (size_t)rr * 256 + 128 + (col - 256));
            }
            BF4 pk;
            pk.a = __float22bfloat162_rn(make_float2(v.x, v.y));
            pk.b = __float22bfloat162_rn(make_float2(v.z, v.w));
            *(BF4*)(xrow + col * 2) = pk;
        }
    }
    __syncthreads();

    const char* wp0 = Wp;
    const char* wp1 = Wp + WP1OFF;
    const char* wp2 = Wp + WP2OFF;

    f32x4 acc[4];

    // ---- GEMM1: X[64,384] @ W0 -> H0 (wave w owns nt = w) ----
#pragma unroll
    for (int mt = 0; mt < 4; ++mt) acc[mt] = (f32x4){0.f, 0.f, 0.f, 0.f};
    gemm_tiles4<8, 12>(lds + REG0, XS_B, wp0, w, lane, acc);
    __syncthreads();                       // Xb dead before Hf overwrite
    dump_acc4(lds + REG0, w, lane, acc, b0[w * 16 + lr]);
    __syncthreads();
    ln_silu_bf(lds + REG0, lds + REG1, ln0s, ln0b, t);   // Hf -> Hb
    __syncthreads();

    // ---- GEMM2: H0[64,128] @ W1 -> H1 ----
#pragma unroll
    for (int mt = 0; mt < 4; ++mt) acc[mt] = (f32x4){0.f, 0.f, 0.f, 0.f};
    gemm_tiles4<8, 4>(lds + REG1, HS_B, wp1, w, lane, acc);
    // no barrier: dump writes REG0 (Hf) whose readers finished before the
    // previous barrier; GEMM2 read REG1 only.
    dump_acc4(lds + REG0, w, lane, acc, b1[w * 16 + lr]);
    __syncthreads();
    ln_silu_bf(lds + REG0, lds + REG1, ln1s, ln1b, t);   // Hf -> Hb
    __syncthreads();

    // ---- issue wigner-compaction loads (complete under GEMM3) ----
    // pairs p in [0, MB*25): e = e0 + p/25, k = p%25 -> 5 floats each.
    float wv[4][5];
    int pe[4], pk_[4];
#pragma unroll
    for (int j = 0; j < 4; ++j) {
        const int p = t + MTHREADS * j;
        pe[j] = -1;
        if (p < MB * 25) {
            const int e = e0 + p / 25;
            if (e < n_edges) {
                pe[j] = e;
                pk_[j] = p % 25;
                const float* src = wigner + (size_t)e * WIG_ROW + pk_[j] * WIG_LD;
#pragma unroll
                for (int m = 0; m < 5; ++m) wv[j][m] = src[m];
            }
        }
    }

    // ---- GEMM3: H1[64,128] @ W2 -> F (x0.2), nt = w, w+8 (<10) ----
#pragma unroll
    for (int p = 0; p < 2; ++p) {
        const int nt = w + 8 * p;
        if (nt >= 10) break;
#pragma unroll
        for (int mt = 0; mt < 4; ++mt) acc[mt] = (f32x4){0.f, 0.f, 0.f, 0.f};
        gemm_tiles4<10, 4>(lds + REG1, HS_B, wp2, nt, lane, acc);
        const float bb = b2[nt * 16 + lr];
#pragma unroll
        for (int mt = 0; mt < 4; ++mt)
#pragma unroll
            for (int i = 0; i < 4; ++i) {
                const int e = e0 + mt * 16 + lk * 4 + i;
                if (e < n_edges)
                    F[(size_t)e * NOUT + nt * 16 + lr] = (acc[mt][i] + bb) * 0.2f;
            }
    }

    // ---- drain compaction stores ----
#pragma unroll
    for (int j = 0; j < 4; ++j) {
        if (pe[j] >= 0) {
            float* dst = wigC + (size_t)pe[j] * 125 + pk_[j] * 5;
#pragma unroll
            for (int m = 0; m < 5; ++m) dst[m] = wv[j][m];
        }
    }
}

// ---------------------------------------------------------------- CSR build
__global__ void hist_kernel(const int* __restrict__ recv, int* __restrict__ cnt, int n_edges)
{
    const int e = blockIdx.x * 256 + threadIdx.x;
    if (e < n_edges) atomicAdd(&cnt[recv[e]], 1);
}

#define SCAN_T 1024
#define SCAN_CH 20
__global__ __launch_bounds__(SCAN_T)
void scan_kernel(const int* __restrict__ cnt, int* __restrict__ offsets,
                 int* __restrict__ cursor, int n_nodes)
{
    __shared__ int waveSum[SCAN_T / 64];
    const int t = threadIdx.x;
    const int base = t * SCAN_CH;
    int local[SCAN_CH];
    int s = 0;
#pragma unroll
    for (int j = 0; j < SCAN_CH; ++j) {
        const int v = (base + j < n_nodes) ? cnt[base + j] : 0;
        local[j] = s;
        s += v;
    }
    const int lane = t & 63;
    int incl = s;
#pragma unroll
    for (int d = 1; d < 64; d <<= 1) {
        const int u = __shfl_up(incl, d, 64);
        if (lane >= d) incl += u;
    }
    if (lane == 63) waveSum[t >> 6] = incl;
    __syncthreads();
    if (t < SCAN_T / 64) {
        const int v = waveSum[t];
        int incl2 = v;
#pragma unroll
        for (int d = 1; d < SCAN_T / 64; d <<= 1) {
            const int u = __shfl_up(incl2, d, 64);
            if (lane >= d) incl2 += u;
        }
        waveSum[t] = incl2 - v;
    }
    __syncthreads();
    const int threadExcl = waveSum[t >> 6] + (incl - s);
#pragma unroll
    for (int j = 0; j < SCAN_CH; ++j)
        if (base + j < n_nodes) {
            const int o = threadExcl + local[j];
            offsets[base + j] = o;
            cursor[base + j] = o;
        }
    if (t == SCAN_T - 1) offsets[n_nodes] = threadExcl + s;
}

__global__ void scatter_kernel(const int* __restrict__ recv, int* __restrict__ cursor,
                               int* __restrict__ elist, int n_edges)
{
    const int e = blockIdx.x * 256 + threadIdx.x;
    if (e < n_edges) {
        const int p = atomicAdd(&cursor[recv[e]], 1);
        elist[p] = e;
    }
}

// ---------------------------------------------------------------- aggregation
// 256 threads per node; reads COMPACT wigC[e][125] (coalesced 500 B/edge).
__global__ __launch_bounds__(256)
void agg_kernel(const float* __restrict__ wigC, const float* __restrict__ F,
                const int* __restrict__ offsets, const int* __restrict__ elist,
                float* __restrict__ out)
{
    const int n = blockIdx.x;
    const int t = threadIdx.x;
    __shared__ float wigS[2][128];

    const int beg = offsets[n];
    const int end = offsets[n + 1];

    const int ch = t & 31;
    const int k0 = t >> 5;
    float a0 = 0.f, a1 = 0.f, a2 = 0.f, a3 = 0.f;

    float f[5];
    if (beg < end) {
        const int e = elist[beg];
        if (t < 125) wigS[0][t] = wigC[(size_t)e * 125 + t];
        const float* Fp = F + (size_t)e * NOUT + ch;
#pragma unroll
        for (int m = 0; m < 5; ++m) f[m] = Fp[m * 32];
    }

    int buf = 0;
    for (int i = beg; i < end; ++i) {
        __syncthreads();
        float fc[5];
#pragma unroll
        for (int m = 0; m < 5; ++m) fc[m] = f[m];
        if (i + 1 < end) {
            const int e = elist[i + 1];
            if (t < 125) wigS[buf ^ 1][t] = wigC[(size_t)e * 125 + t];
            const float* Fp = F + (size_t)e * NOUT + ch;
#pragma unroll
            for (int m = 0; m < 5; ++m) f[m] = Fp[m * 32];
        }
        const float* wp = &wigS[buf][0];
        { const float* wq = wp + k0 * 5;        a0 += wq[0]*fc[0] + wq[1]*fc[1] + wq[2]*fc[2] + wq[3]*fc[3] + wq[4]*fc[4]; }
        { const float* wq = wp + (k0 + 8) * 5;  a1 += wq[0]*fc[0] + wq[1]*fc[1] + wq[2]*fc[2] + wq[3]*fc[3] + wq[4]*fc[4]; }
        { const float* wq = wp + (k0 + 16) * 5; a2 += wq[0]*fc[0] + wq[1]*fc[1] + wq[2]*fc[2] + wq[3]*fc[3] + wq[4]*fc[4]; }
        if (t < 32) { const float* wq = wp + 120; a3 += wq[0]*fc[0] + wq[1]*fc[1] + wq[2]*fc[2] + wq[3]*fc[3] + wq[4]*fc[4]; }
        buf ^= 1;
    }

    float* orow = out + (size_t)n * (NKF * 32);
    orow[t] = a0;
    orow[t + 256] = a1;
    orow[t + 512] = a2;
    if (t < 32) orow[t + 768] = a3;
}

// ---------------------------------------------------------------- fallback (round-0)
#define EB 32
__device__ __forceinline__ void ln_silu_f(float (*Bx)[HDIM], const float* __restrict__ s,
                                          const float* __restrict__ b, int t)
{
    const int r = t >> 3;
    const int j = t & 7;
    float v[16];
    float sum = 0.f, sq = 0.f;
#pragma unroll
    for (int q = 0; q < 16; ++q) { v[q] = Bx[r][j*16+q]; sum += v[q]; sq = fmaf(v[q], v[q], sq); }
#pragma unroll
    for (int m = 1; m < 8; m <<= 1) { sum += __shfl_xor(sum, m, 64); sq += __shfl_xor(sq, m, 64); }
    const float mu = sum * (1.f/HDIM);
    const float var = sq * (1.f/HDIM) - mu*mu;
    const float rstd = rsqrtf(var + 1e-6f);
#pragma unroll
    for (int q = 0; q < 16; ++q) {
        const int cc = j*16+q;
        const float y = (v[q]-mu)*rstd*s[cc]+b[cc];
        Bx[r][cc] = y / (1.f + __expf(-y));
    }
}

__global__ __launch_bounds__(256, 2)
void edge_fused_kernel(
    const int* __restrict__ species, const float* __restrict__ edge_embeds,
    const int* __restrict__ senders, const int* __restrict__ receivers,
    const float* __restrict__ wigner, const float* __restrict__ embed_table,
    const float* __restrict__ W0, const float* __restrict__ b0,
    const float* __restrict__ ln0s, const float* __restrict__ ln0b,
    const float* __restrict__ W1, const float* __restrict__ b1,
    const float* __restrict__ ln1s, const float* __restrict__ ln1b,
    const float* __restrict__ W2, const float* __restrict__ b2,
    float* __restrict__ out, int n_edges)
{
    __shared__ float A[EB][DIN];
    __shared__ float Bx[EB][HDIM];
    __shared__ int sSpec[EB], rSpec[EB], rNode[EB];
    const int t = threadIdx.x;
    const int e0 = blockIdx.x * EB;
    if (t < EB) {
        const int e = e0 + t;
        int s = 0, r = 0;
        if (e < n_edges) { s = senders[e]; r = receivers[e]; }
        sSpec[t] = species[s]; rSpec[t] = species[r]; rNode[t] = r;
    }
    __syncthreads();
    for (int idx = t; idx < EB * DIN; idx += 256) {
        const int r = idx / DIN;
        const int i = idx - r * DIN;
        const int e = e0 + r;
        float v = 0.f;
        if (e < n_edges) {
            if (i < HDIM) v = edge_embeds[(size_t)e * HDIM + i];
            else if (i < 2*HDIM) v = embed_table[(size_t)sSpec[r]*256 + (i-HDIM)];
            else v = embed_table[(size_t)rSpec[r]*256 + HDIM + (i-2*HDIM)];
        }
        A[r][i] = v;
    }
    __syncthreads();
    const int c = t & (HDIM-1);
    const int g = t >> 7;
    float acc[16];
#pragma unroll
    for (int q = 0; q < 16; ++q) acc[q] = 0.f;
    for (int it = 0; it < DIN/4; ++it) {
        const float wa = W0[(4*it+0)*HDIM+c], wb = W0[(4*it+1)*HDIM+c];
        const float wc = W0[(4*it+2)*HDIM+c], wd = W0[(4*it+3)*HDIM+c];
#pragma unroll
        for (int q = 0; q < 16; ++q) {
            const float4 x4 = *reinterpret_cast<const float4*>(&A[g*16+q][4*it]);
            acc[q] = fmaf(x4.x, wa, fmaf(x4.y, wb, fmaf(x4.z, wc, fmaf(x4.w, wd, acc[q]))));
        }
    }
    { const float bb = b0[c];
#pragma unroll
      for (int q = 0; q < 16; ++q) Bx[g*16+q][c] = acc[q] + bb; }
    __syncthreads(); ln_silu_f(Bx, ln0s, ln0b, t); __syncthreads();
#pragma unroll
    for (int q = 0; q < 16; ++q) acc[q] = 0.f;
    for (int it = 0; it < HDIM/4; ++it) {
        const float wa = W1[(4*it+0)*HDIM+c], wb = W1[(4*it+1)*HDIM+c];
        const float wc = W1[(4*it+2)*HDIM+c], wd = W1[(4*it+3)*HDIM+c];
#pragma unroll
        for (int q = 0; q < 16; ++q) {
            const float4 x4 = *reinterpret_cast<const float4*>(&Bx[g*16+q][4*it]);
            acc[q] = fmaf(x4.x, wa, fmaf(x4.y, wb, fmaf(x4.z, wc, fmaf(x4.w, wd, acc[q]))));
        }
    }
    __syncthreads();
    { const float bb = b1[c];
#pragma unroll
      for (int q = 0; q < 16; ++q) Bx[g*16+q][c] = acc[q] + bb; }
    __syncthreads(); ln_silu_f(Bx, ln1s, ln1b, t); __syncthreads();
    float* Ff = &A[0][0];
    {
        float a2[16];
#pragma unroll
        for (int q = 0; q < 16; ++q) a2[q] = 0.f;
        for (int it = 0; it < HDIM/4; ++it) {
            const float wa = W2[(4*it+0)*NOUT+c], wb = W2[(4*it+1)*NOUT+c];
            const float wc = W2[(4*it+2)*NOUT+c], wd = W2[(4*it+3)*NOUT+c];
#pragma unroll
            for (int q = 0; q < 16; ++q) {
                const float4 x4 = *reinterpret_cast<const float4*>(&Bx[g*16+q][4*it]);
                a2[q] = fmaf(x4.x, wa, fmaf(x4.y, wb, fmaf(x4.z, wc, fmaf(x4.w, wd, a2[q]))));
            }
        }
        const float bb = b2[c];
#pragma unroll
        for (int q = 0; q < 16; ++q) Ff[(g*16+q)*NOUT+c] = (a2[q]+bb)*0.2f;
    }
    {
        const int c2 = HDIM + (t & 31);
        const int g8 = t >> 5;
        float a2[4] = {0.f, 0.f, 0.f, 0.f};
        for (int it = 0; it < HDIM/4; ++it) {
            const float wa = W2[(4*it+0)*NOUT+c2], wb = W2[(4*it+1)*NOUT+c2];
            const float wc = W2[(4*it+2)*NOUT+c2], wd = W2[(4*it+3)*NOUT+c2];
#pragma unroll
            for (int q = 0; q < 4; ++q) {
                const float4 x4 = *reinterpret_cast<const float4*>(&Bx[g8*4+q][4*it]);
                a2[q] = fmaf(x4.x, wa, fmaf(x4.y, wb, fmaf(x4.z, wc, fmaf(x4.w, wd, a2[q]))));
            }
        }
        const float bb = b2[c2];
#pragma unroll
        for (int q = 0; q < 4; ++q) Ff[(g8*4+q)*NOUT+c2] = (a2[q]+bb)*0.2f;
    }
    __syncthreads();
    for (int r = 0; r < EB; ++r) {
        const int e = e0 + r;
        if (e >= n_edges) break;
        const float* wrow = wigner + (size_t)e * WIG_ROW;
        float* orow = out + (size_t)rNode[r] * (NKF*32);
        const float* Fr = Ff + r * NOUT;
#pragma unroll
        for (int jj = 0; jj < 4; ++jj) {
            const int p = t + 256*jj;
            if (p < NKF*32) {
                const int k = p >> 5, chh = p & 31;
                float val = 0.f;
#pragma unroll
                for (int m = 0; m < 5; ++m)
                    val = fmaf(wrow[k*WIG_LD+m], Fr[m*32+chh], val);
                atomicAdd(&orow[p], val);
            }
        }
    }
}

// ---------------------------------------------------------------- launch
extern "C" void kernel_launch(void* const* d_in, const int* in_sizes, int n_in,
                              void* d_out, int out_size, void* d_ws, size_t ws_size,
                              hipStream_t stream)
{
    const int*   species     = (const int*)d_in[0];
    const float* edge_embeds = (const float*)d_in[1];
    const int*   senders     = (const int*)d_in[2];
    const int*   receivers   = (const int*)d_in[3];
    const float* wigner      = (const float*)d_in[4];
    const float* embed_table = (const float*)d_in[5];
    const float* W0 = (const float*)d_in[6];
    const float* b0 = (const float*)d_in[7];
    const float* ln0s = (const float*)d_in[8];
    const float* ln0b = (const float*)d_in[9];
    const float* W1 = (const float*)d_in[10];
    const float* b1 = (const float*)d_in[11];
    const float* ln1s = (const float*)d_in[12];
    const float* ln1b = (const float*)d_in[13];
    const float* W2 = (const float*)d_in[14];
    const float* b2 = (const float*)d_in[15];
    float* out = (float*)d_out;

    const int n_nodes = in_sizes[0];
    const int n_edges = in_sizes[2];

    const size_t wpBytes   = WPBYTES;
    const size_t fBytes    = (size_t)n_edges * NOUT * sizeof(float);
    const size_t wcBytes   = (size_t)n_edges * 125 * sizeof(float);
    const size_t offBytes  = (size_t)(n_nodes + 1) * sizeof(int);
    const size_t curBytes  = (size_t)n_nodes * sizeof(int);
    const size_t listBytes = (size_t)n_edges * sizeof(int);
    const size_t need = wpBytes + fBytes + wcBytes + offBytes + curBytes + listBytes + 64;

    if (ws_size < need || n_nodes > SCAN_T * SCAN_CH || n_edges <= 0) {
        hipMemsetAsync(out, 0, (size_t)out_size * sizeof(float), stream);
        const int nblocks = (n_edges + EB - 1) / EB;
        hipLaunchKernelGGL(edge_fused_kernel, dim3(nblocks), dim3(256), 0, stream,
                           species, edge_embeds, senders, receivers, wigner, embed_table,
                           W0, b0, ln0s, ln0b, W1, b1, ln1s, ln1b, W2, b2, out, n_edges);
        return;
    }

    char* ws = (char*)d_ws;
    unsigned short* Wp = (unsigned short*)ws;
    float* F       = (float*)(ws + wpBytes);
    float* wigC    = (float*)(ws + wpBytes + fBytes);
    int*   offsets = (int*)(ws + wpBytes + fBytes + wcBytes);
    int*   cursor  = (int*)(ws + wpBytes + fBytes + wcBytes + offBytes);
    int*   elist   = (int*)(ws + wpBytes + fBytes + wcBytes + offBytes + curBytes);

    const int egrid = (n_edges + 255) / 256;

    // weight repack (tiny; L2-resident afterwards)
    hipLaunchKernelGGL(repack_w, dim3(336), dim3(256), 0, stream, W0, W1, W2, Wp);

    // CSR build (scan also initializes cursor)
    hipMemsetAsync(cursor, 0, curBytes, stream);
    hipLaunchKernelGGL(hist_kernel, dim3(egrid), dim3(256), 0, stream,
                       receivers, cursor, n_edges);
    hipLaunchKernelGGL(scan_kernel, dim3(1), dim3(SCAN_T), 0, stream,
                       cursor, offsets, cursor, n_nodes);
    hipLaunchKernelGGL(scatter_kernel, dim3(egrid), dim3(256), 0, stream,
                       receivers, cursor, elist, n_edges);

    // MLP (MFMA, MB=64, single-term weights, B-prefetch) + wigner compaction
    const int mblocks = (n_edges + MB - 1) / MB;
    hipLaunchKernelGGL(mlp_mfma, dim3(mblocks), dim3(MTHREADS), 0, stream,
                       species, edge_embeds, senders, receivers, embed_table,
                       (const char*)Wp, b0, ln0s, ln0b, b1, ln1s, ln1b, b2,
                       wigner, wigC, F, n_edges);

    // gather-aggregate -> out (256 thr/node, compact wigner)
    hipLaunchKernelGGL(agg_kernel, dim3(n_nodes), dim3(256), 0, stream,
                       wigC, F, offsets, elist, out);
}

// Round 12
// 530.031 us; speedup vs baseline: 1.3268x; 1.3268x over previous
//
#include <hip/hip_runtime.h>
#include <hip/hip_bf16.h>
#include <cstddef>

// EdgeDegreeEmbedding, round 11 = round 9 with A-fragment reuse in the MLP.
//  - r10 post-mortem: wigner compaction reverted (wigner is read once per
//    edge -> compaction can't reduce bytes; it serialized into mlp, +200us).
//  - Ledger: r9 mlp issues 768 ds_read_b128 A-frags per block (1 per MFMA),
//    ~9.2k of ~13k LDS-pipe cycles -> LDS-issue-bound.
//  - Fix: wave w owns 1 M-tile (mt=w&3) x 4 N-tiles (ntg=(w>>2)*4); each
//    A-read feeds 4 MFMA (5 in GEMM3). A-reads/block 768 -> 160. B-frags
//    duplicated 4x across waves (L2-resident Wp, ~56us of L2 BW total).
//  - All fragment layouts / repack / LN / barriers identical to r9 (proven
//    absmax 0.03125). agg = r9 256-thr version. CSR + fallback unchanged.

#define MB 64
#define MTHREADS 512
#define DIN 384
#define HDIM 128
#define NOUT 160
#define NKF 25
#define WIG_LD 19
#define WIG_ROW 475

#define WP1OFF 98304     // bytes: W0 pack = 12kt*8nt*1024
#define WP2OFF 131072    // + W1 pack 4*8*1024 = 32768
#define WPBYTES 172032   // + W2 pack 4*10*1024 = 40960

// LDS layout (bytes)
#define XS_B   784       // Xb row stride: (384+8) bf16
#define FS_B   528       // Hf row stride: 132 f32
#define HS_B   272       // Hb row stride: (128+8) bf16
#define REG0   0         // Xb (64*784=50176) / Hf (64*528=33792)
#define REG1   50176     // Hb (64*272=17408)
#define METAS  67584     // sS[64]
#define METAR  67840     // rS[64]
#define LDSSZ  68096

typedef __attribute__((ext_vector_type(8))) short short8;
typedef __attribute__((ext_vector_type(4))) float f32x4;

struct BF4 { __hip_bfloat162 a, b; };   // 8 B = 4 bf16

__device__ __forceinline__ unsigned short f2bf(float f)
{
    union { float f; unsigned u; } x; x.f = f;
    unsigned r = x.u + 0x7fffu + ((x.u >> 16) & 1u);
    return (unsigned short)(r >> 16);
}

// ---------------------------------------------------------------- W repack
// B-frag block (1024 B) = one (kt, nt): 64 lanes x 8 bf16.
// lane l holds B[kt*32 + 8*(l>>4)+i][nt*16 + (l&15)]. Single term (RN bf16).
__global__ void repack_w(const float* __restrict__ W0, const float* __restrict__ W1,
                         const float* __restrict__ W2, unsigned short* __restrict__ Wp)
{
    const int id = blockIdx.x * 256 + threadIdx.x;
    const float* W; int k, n, NT, N; size_t base;  // base in ushort units
    if (id < 49152)      { W = W0; k = id >> 7;  n = id & 127;  NT = 8;  N = 128; base = 0; }
    else if (id < 65536) { int r = id - 49152; W = W1; k = r >> 7; n = r & 127; NT = 8; N = 128; base = 49152; }
    else if (id < 86016) { int r = id - 65536; W = W2; k = r / 160; n = r - 160 * k; NT = 10; N = 160; base = 65536; }
    else return;
    const float w = W[(size_t)k * N + n];
    const int kt = k >> 5, kk = k & 31;
    const int l = ((kk >> 3) << 4) | (n & 15);
    const int i = kk & 7;
    const int nt = n >> 4;
    Wp[base + (size_t)(kt * NT + nt) * 512 + l * 8 + i] = f2bf(w);
}

// ---------------------------------------------------------------- GEMM core
// Wave owns 1 M-tile (mt) x NP N-tiles (ntg..ntg+NP-1): per kt, ONE A-frag
// LDS read feeds NP MFMAs (B-frags from L2-resident Wp).
template<int NT, int KT, int NP>
__device__ __forceinline__ void gemm_1xN(const char* __restrict__ ldsA, int astride,
                                         const char* __restrict__ wp,
                                         int mt, int ntg, int lane, f32x4 acc[NP])
{
    const int lr = lane & 15, lk = lane >> 4;
#pragma unroll
    for (int kt = 0; kt < KT; ++kt) {
        const short8 a = *(const short8*)(ldsA + (mt * 16 + lr) * astride + kt * 64 + lk * 16);
        short8 b[NP];
#pragma unroll
        for (int p = 0; p < NP; ++p)
            b[p] = *(const short8*)(wp + (size_t)(kt * NT + ntg + p) * 1024 + lane * 16);
#pragma unroll
        for (int p = 0; p < NP; ++p)
            acc[p] = __builtin_amdgcn_mfma_f32_16x16x32_bf16(a, b[p], acc[p], 0, 0, 0);
    }
}

// dump 4 accumulated 16x16 tiles (one mt row, nt = ntg..ntg+3) to Hf + bias.
__device__ __forceinline__ void dump_1x4(char* Hf, int mt, int ntg, int lane,
                                         const f32x4 acc[4], const float* __restrict__ bi)
{
    const int lr = lane & 15, lk = lane >> 4;
#pragma unroll
    for (int p = 0; p < 4; ++p) {
        const int col = (ntg + p) * 16 + lr;
        const float bb = bi[col];
#pragma unroll
        for (int i = 0; i < 4; ++i)
            *(float*)(Hf + (mt * 16 + lk * 4 + i) * FS_B + col * 4) = acc[p][i] + bb;
    }
}

// LN + silu: read f32 (FS_B), write packed bf16 (HS_B). 512 thr, 64 rows,
// 8 threads/row x 16 channels.  (r9 verbatim)
__device__ __forceinline__ void ln_silu_bf(const char* Hf, char* Hb,
                                           const float* __restrict__ s,
                                           const float* __restrict__ b, int t)
{
    const int j = t & 7;
    const int r = t >> 3;
    float v[16];
    float sum = 0.f, sq = 0.f;
#pragma unroll
    for (int q4 = 0; q4 < 4; ++q4) {
        const float4 x4 = *(const float4*)(Hf + r * FS_B + (j * 16 + q4 * 4) * 4);
        v[q4 * 4 + 0] = x4.x; v[q4 * 4 + 1] = x4.y;
        v[q4 * 4 + 2] = x4.z; v[q4 * 4 + 3] = x4.w;
    }
#pragma unroll
    for (int q = 0; q < 16; ++q) { sum += v[q]; sq = fmaf(v[q], v[q], sq); }
#pragma unroll
    for (int m = 1; m < 8; m <<= 1) {
        sum += __shfl_xor(sum, m, 64);
        sq  += __shfl_xor(sq,  m, 64);
    }
    const float mu = sum * (1.f / 128.f);
    const float var = sq * (1.f / 128.f) - mu * mu;
    const float rstd = rsqrtf(var + 1e-6f);
#pragma unroll
    for (int q = 0; q < 16; q += 2) {
        const int c0 = j * 16 + q;
        float y0 = (v[q] - mu) * rstd * s[c0] + b[c0];
        float y1 = (v[q + 1] - mu) * rstd * s[c0 + 1] + b[c0 + 1];
        y0 = y0 / (1.f + __expf(-y0));
        y1 = y1 / (1.f + __expf(-y1));
        *(__hip_bfloat162*)(Hb + r * HS_B + c0 * 2) =
            __float22bfloat162_rn(make_float2(y0, y1));
    }
}

// ---------------------------------------------------------------- MLP (MFMA)
__global__ __launch_bounds__(MTHREADS, 2)
void mlp_mfma(
    const int* __restrict__ species,
    const float* __restrict__ edge_embeds,
    const int* __restrict__ senders,
    const int* __restrict__ receivers,
    const float* __restrict__ embed_table,
    const char* __restrict__ Wp,
    const float* __restrict__ b0, const float* __restrict__ ln0s, const float* __restrict__ ln0b,
    const float* __restrict__ b1, const float* __restrict__ ln1s, const float* __restrict__ ln1b,
    const float* __restrict__ b2,
    float* __restrict__ F,
    int n_edges)
{
    __shared__ alignas(16) char lds[LDSSZ];
    int* sS = (int*)(lds + METAS);
    int* rS = (int*)(lds + METAR);

    const int t = threadIdx.x;
    const int e0 = blockIdx.x * MB;
    const int w = t >> 6;
    const int lane = t & 63;
    const int lr = lane & 15, lk = lane >> 4;

    const int mt = w & 3;              // M-tile (rows mt*16..mt*16+15)
    const int ntg = (w >> 2) * 4;      // N-tile group for GEMM1/2 (4 tiles)
    const int ntg3 = (w >> 2) * 5;     // N-tile group for GEMM3 (5 tiles)

    if (t < MB) {
        const int e = e0 + t;
        int s = 0, r = 0;
        if (e < n_edges) { s = senders[e]; r = receivers[e]; }
        sS[t] = species[s];
        rS[t] = species[r];
    }
    __syncthreads();

    // ---- stage X -> bf16 LDS (8 threads/row, 4-col chunks, stride 32) ----
    {
        const int row = t >> 3;            // 0..63
        const int e = e0 + row;
        const bool ev = e < n_edges;
        const int ss = sS[row], rr = rS[row];
        char* xrow = lds + REG0 + row * XS_B;
        const int c0 = (t & 7) * 4;
#pragma unroll
        for (int jj = 0; jj < 12; ++jj) {
            const int col = c0 + 32 * jj;   // jj<4: edge; jj<8: sender; else recv
            float4 v = make_float4(0.f, 0.f, 0.f, 0.f);
            if (ev) {
                if (jj < 4)
                    v = *(const float4*)(edge_embeds + (size_t)e * 128 + col);
                else if (jj < 8)
                    v = *(const float4*)(embed_table + (size_t)ss * 256 + (col - 128));
                else
                    v = *(const float4*)(embed_table + (size_t)rr * 256 + 128 + (col - 256));
            }
            BF4 pk;
            pk.a = __float22bfloat162_rn(make_float2(v.x, v.y));
            pk.b = __float22bfloat162_rn(make_float2(v.z, v.w));
            *(BF4*)(xrow + col * 2) = pk;
        }
    }
    __syncthreads();

    const char* wp0 = Wp;
    const char* wp1 = Wp + WP1OFF;
    const char* wp2 = Wp + WP2OFF;

    f32x4 acc[4];

    // ---- GEMM1: X[64,384] @ W0 -> H0 ----
#pragma unroll
    for (int p = 0; p < 4; ++p) acc[p] = (f32x4){0.f, 0.f, 0.f, 0.f};
    gemm_1xN<8, 12, 4>(lds + REG0, XS_B, wp0, mt, ntg, lane, acc);
    __syncthreads();                       // Xb dead before Hf overwrite
    dump_1x4(lds + REG0, mt, ntg, lane, acc, b0);
    __syncthreads();
    ln_silu_bf(lds + REG0, lds + REG1, ln0s, ln0b, t);   // Hf -> Hb
    __syncthreads();

    // ---- GEMM2: H0[64,128] @ W1 -> H1 ----
#pragma unroll
    for (int p = 0; p < 4; ++p) acc[p] = (f32x4){0.f, 0.f, 0.f, 0.f};
    gemm_1xN<8, 4, 4>(lds + REG1, HS_B, wp1, mt, ntg, lane, acc);
    // no barrier: dump writes REG0 (Hf) whose readers finished before the
    // previous barrier; GEMM2 read REG1 only.
    dump_1x4(lds + REG0, mt, ntg, lane, acc, b1);
    __syncthreads();
    ln_silu_bf(lds + REG0, lds + REG1, ln1s, ln1b, t);   // Hf -> Hb
    __syncthreads();

    // ---- GEMM3: H1[64,128] @ W2 -> F (x0.2), 5 nt per wave ----
    f32x4 a3[5];
#pragma unroll
    for (int p = 0; p < 5; ++p) a3[p] = (f32x4){0.f, 0.f, 0.f, 0.f};
    gemm_1xN<10, 4, 5>(lds + REG1, HS_B, wp2, mt, ntg3, lane, a3);
#pragma unroll
    for (int p = 0; p < 5; ++p) {
        const int col = (ntg3 + p) * 16 + lr;
        const float bb = b2[col];
#pragma unroll
        for (int i = 0; i < 4; ++i) {
            const int e = e0 + mt * 16 + lk * 4 + i;
            if (e < n_edges)
                F[(size_t)e * NOUT + col] = (a3[p][i] + bb) * 0.2f;
        }
    }
}

// ---------------------------------------------------------------- CSR build
__global__ void hist_kernel(const int* __restrict__ recv, int* __restrict__ cnt, int n_edges)
{
    const int e = blockIdx.x * 256 + threadIdx.x;
    if (e < n_edges) atomicAdd(&cnt[recv[e]], 1);
}

#define SCAN_T 1024
#define SCAN_CH 20
__global__ __launch_bounds__(SCAN_T)
void scan_kernel(const int* __restrict__ cnt, int* __restrict__ offsets,
                 int* __restrict__ cursor, int n_nodes)
{
    __shared__ int waveSum[SCAN_T / 64];
    const int t = threadIdx.x;
    const int base = t * SCAN_CH;
    int local[SCAN_CH];
    int s = 0;
#pragma unroll
    for (int j = 0; j < SCAN_CH; ++j) {
        const int v = (base + j < n_nodes) ? cnt[base + j] : 0;
        local[j] = s;
        s += v;
    }
    const int lane = t & 63;
    int incl = s;
#pragma unroll
    for (int d = 1; d < 64; d <<= 1) {
        const int u = __shfl_up(incl, d, 64);
        if (lane >= d) incl += u;
    }
    if (lane == 63) waveSum[t >> 6] = incl;
    __syncthreads();
    if (t < SCAN_T / 64) {
        const int v = waveSum[t];
        int incl2 = v;
#pragma unroll
        for (int d = 1; d < SCAN_T / 64; d <<= 1) {
            const int u = __shfl_up(incl2, d, 64);
            if (lane >= d) incl2 += u;
        }
        waveSum[t] = incl2 - v;
    }
    __syncthreads();
    const int threadExcl = waveSum[t >> 6] + (incl - s);
#pragma unroll
    for (int j = 0; j < SCAN_CH; ++j)
        if (base + j < n_nodes) {
            const int o = threadExcl + local[j];
            offsets[base + j] = o;
            cursor[base + j] = o;
        }
    if (t == SCAN_T - 1) offsets[n_nodes] = threadExcl + s;
}

__global__ void scatter_kernel(const int* __restrict__ recv, int* __restrict__ cursor,
                               int* __restrict__ elist, int n_edges)
{
    const int e = blockIdx.x * 256 + threadIdx.x;
    if (e < n_edges) {
        const int p = atomicAdd(&cursor[recv[e]], 1);
        elist[p] = e;
    }
}

// ---------------------------------------------------------------- aggregation
// 256 threads per node (r9/r3 version): ch=t&31, k0=t>>5 covers k0, k0+8,
// k0+16 (+24 for t<32); F reg-prefetched; wigner LDS double-buffered.
__global__ __launch_bounds__(256)
void agg_kernel(const float* __restrict__ wigner, const float* __restrict__ F,
                const int* __restrict__ offsets, const int* __restrict__ elist,
                float* __restrict__ out)
{
    const int n = blockIdx.x;
    const int t = threadIdx.x;
    __shared__ float wigS[2][128];

    const int beg = offsets[n];
    const int end = offsets[n + 1];

    const int ch = t & 31;
    const int k0 = t >> 5;
    float a0 = 0.f, a1 = 0.f, a2 = 0.f, a3 = 0.f;

    float f[5];
    if (beg < end) {
        const int e = elist[beg];
        if (t < 125) wigS[0][t] = wigner[(size_t)e * WIG_ROW + (t / 5) * WIG_LD + (t % 5)];
        const float* Fp = F + (size_t)e * NOUT + ch;
#pragma unroll
        for (int m = 0; m < 5; ++m) f[m] = Fp[m * 32];
    }

    int buf = 0;
    for (int i = beg; i < end; ++i) {
        __syncthreads();
        float fc[5];
#pragma unroll
        for (int m = 0; m < 5; ++m) fc[m] = f[m];
        if (i + 1 < end) {
            const int e = elist[i + 1];
            if (t < 125) wigS[buf ^ 1][t] = wigner[(size_t)e * WIG_ROW + (t / 5) * WIG_LD + (t % 5)];
            const float* Fp = F + (size_t)e * NOUT + ch;
#pragma unroll
            for (int m = 0; m < 5; ++m) f[m] = Fp[m * 32];
        }
        const float* wp = &wigS[buf][0];
        { const float* wq = wp + k0 * 5;        a0 += wq[0]*fc[0] + wq[1]*fc[1] + wq[2]*fc[2] + wq[3]*fc[3] + wq[4]*fc[4]; }
        { const float* wq = wp + (k0 + 8) * 5;  a1 += wq[0]*fc[0] + wq[1]*fc[1] + wq[2]*fc[2] + wq[3]*fc[3] + wq[4]*fc[4]; }
        { const float* wq = wp + (k0 + 16) * 5; a2 += wq[0]*fc[0] + wq[1]*fc[1] + wq[2]*fc[2] + wq[3]*fc[3] + wq[4]*fc[4]; }
        if (t < 32) { const float* wq = wp + 120; a3 += wq[0]*fc[0] + wq[1]*fc[1] + wq[2]*fc[2] + wq[3]*fc[3] + wq[4]*fc[4]; }
        buf ^= 1;
    }

    float* orow = out + (size_t)n * (NKF * 32);
    orow[t] = a0;
    orow[t + 256] = a1;
    orow[t + 512] = a2;
    if (t < 32) orow[t + 768] = a3;
}

// ---------------------------------------------------------------- fallback (round-0)
#define EB 32
__device__ __forceinline__ void ln_silu_f(float (*Bx)[HDIM], const float* __restrict__ s,
                                          const float* __restrict__ b, int t)
{
    const int r = t >> 3;
    const int j = t & 7;
    float v[16];
    float sum = 0.f, sq = 0.f;
#pragma unroll
    for (int q = 0; q < 16; ++q) { v[q] = Bx[r][j*16+q]; sum += v[q]; sq = fmaf(v[q], v[q], sq); }
#pragma unroll
    for (int m = 1; m < 8; m <<= 1) { sum += __shfl_xor(sum, m, 64); sq += __shfl_xor(sq, m, 64); }
    const float mu = sum * (1.f/HDIM);
    const float var = sq * (1.f/HDIM) - mu*mu;
    const float rstd = rsqrtf(var + 1e-6f);
#pragma unroll
    for (int q = 0; q < 16; ++q) {
        const int cc = j*16+q;
        const float y = (v[q]-mu)*rstd*s[cc]+b[cc];
        Bx[r][cc] = y / (1.f + __expf(-y));
    }
}

__global__ __launch_bounds__(256, 2)
void edge_fused_kernel(
    const int* __restrict__ species, const float* __restrict__ edge_embeds,
    const int* __restrict__ senders, const int* __restrict__ receivers,
    const float* __restrict__ wigner, const float* __restrict__ embed_table,
    const float* __restrict__ W0, const float* __restrict__ b0,
    const float* __restrict__ ln0s, const float* __restrict__ ln0b,
    const float* __restrict__ W1, const float* __restrict__ b1,
    const float* __restrict__ ln1s, const float* __restrict__ ln1b,
    const float* __restrict__ W2, const float* __restrict__ b2,
    float* __restrict__ out, int n_edges)
{
    __shared__ float A[EB][DIN];
    __shared__ float Bx[EB][HDIM];
    __shared__ int sSpec[EB], rSpec[EB], rNode[EB];
    const int t = threadIdx.x;
    const int e0 = blockIdx.x * EB;
    if (t < EB) {
        const int e = e0 + t;
        int s = 0, r = 0;
        if (e < n_edges) { s = senders[e]; r = receivers[e]; }
        sSpec[t] = species[s]; rSpec[t] = species[r]; rNode[t] = r;
    }
    __syncthreads();
    for (int idx = t; idx < EB * DIN; idx += 256) {
        const int r = idx / DIN;
        const int i = idx - r * DIN;
        const int e = e0 + r;
        float v = 0.f;
        if (e < n_edges) {
            if (i < HDIM) v = edge_embeds[(size_t)e * HDIM + i];
            else if (i < 2*HDIM) v = embed_table[(size_t)sSpec[r]*256 + (i-HDIM)];
            else v = embed_table[(size_t)rSpec[r]*256 + HDIM + (i-2*HDIM)];
        }
        A[r][i] = v;
    }
    __syncthreads();
    const int c = t & (HDIM-1);
    const int g = t >> 7;
    float acc[16];
#pragma unroll
    for (int q = 0; q < 16; ++q) acc[q] = 0.f;
    for (int it = 0; it < DIN/4; ++it) {
        const float wa = W0[(4*it+0)*HDIM+c], wb = W0[(4*it+1)*HDIM+c];
        const float wc = W0[(4*it+2)*HDIM+c], wd = W0[(4*it+3)*HDIM+c];
#pragma unroll
        for (int q = 0; q < 16; ++q) {
            const float4 x4 = *reinterpret_cast<const float4*>(&A[g*16+q][4*it]);
            acc[q] = fmaf(x4.x, wa, fmaf(x4.y, wb, fmaf(x4.z, wc, fmaf(x4.w, wd, acc[q]))));
        }
    }
    { const float bb = b0[c];
#pragma unroll
      for (int q = 0; q < 16; ++q) Bx[g*16+q][c] = acc[q] + bb; }
    __syncthreads(); ln_silu_f(Bx, ln0s, ln0b, t); __syncthreads();
#pragma unroll
    for (int q = 0; q < 16; ++q) acc[q] = 0.f;
    for (int it = 0; it < HDIM/4; ++it) {
        const float wa = W1[(4*it+0)*HDIM+c], wb = W1[(4*it+1)*HDIM+c];
        const float wc = W1[(4*it+2)*HDIM+c], wd = W1[(4*it+3)*HDIM+c];
#pragma unroll
        for (int q = 0; q < 16; ++q) {
            const float4 x4 = *reinterpret_cast<const float4*>(&Bx[g*16+q][4*it]);
            acc[q] = fmaf(x4.x, wa, fmaf(x4.y, wb, fmaf(x4.z, wc, fmaf(x4.w, wd, acc[q]))));
        }
    }
    __syncthreads();
    { const float bb = b1[c];
#pragma unroll
      for (int q = 0; q < 16; ++q) Bx[g*16+q][c] = acc[q] + bb; }
    __syncthreads(); ln_silu_f(Bx, ln1s, ln1b, t); __syncthreads();
    float* Ff = &A[0][0];
    {
        float a2[16];
#pragma unroll
        for (int q = 0; q < 16; ++q) a2[q] = 0.f;
        for (int it = 0; it < HDIM/4; ++it) {
            const float wa = W2[(4*it+0)*NOUT+c], wb = W2[(4*it+1)*NOUT+c];
            const float wc = W2[(4*it+2)*NOUT+c], wd = W2[(4*it+3)*NOUT+c];
#pragma unroll
            for (int q = 0; q < 16; ++q) {
                const float4 x4 = *reinterpret_cast<const float4*>(&Bx[g*16+q][4*it]);
                a2[q] = fmaf(x4.x, wa, fmaf(x4.y, wb, fmaf(x4.z, wc, fmaf(x4.w, wd, a2[q]))));
            }
        }
        const float bb = b2[c];
#pragma unroll
        for (int q = 0; q < 16; ++q) Ff[(g*16+q)*NOUT+c] = (a2[q]+bb)*0.2f;
    }
    {
        const int c2 = HDIM + (t & 31);
        const int g8 = t >> 5;
        float a2[4] = {0.f, 0.f, 0.f, 0.f};
        for (int it = 0; it < HDIM/4; ++it) {
            const float wa = W2[(4*it+0)*NOUT+c2], wb = W2[(4*it+1)*NOUT+c2];
            const float wc = W2[(4*it+2)*NOUT+c2], wd = W2[(4*it+3)*NOUT+c2];
#pragma unroll
            for (int q = 0; q < 4; ++q) {
                const float4 x4 = *reinterpret_cast<const float4*>(&Bx[g8*4+q][4*it]);
                a2[q] = fmaf(x4.x, wa, fmaf(x4.y, wb, fmaf(x4.z, wc, fmaf(x4.w, wd, a2[q]))));
            }
        }
        const float bb = b2[c2];
#pragma unroll
        for (int q = 0; q < 4; ++q) Ff[(g8*4+q)*NOUT+c2] = (a2[q]+bb)*0.2f;
    }
    __syncthreads();
    for (int r = 0; r < EB; ++r) {
        const int e = e0 + r;
        if (e >= n_edges) break;
        const float* wrow = wigner + (size_t)e * WIG_ROW;
        float* orow = out + (size_t)rNode[r] * (NKF*32);
        const float* Fr = Ff + r * NOUT;
#pragma unroll
        for (int jj = 0; jj < 4; ++jj) {
            const int p = t + 256*jj;
            if (p < NKF*32) {
                const int k = p >> 5, chh = p & 31;
                float val = 0.f;
#pragma unroll
                for (int m = 0; m < 5; ++m)
                    val = fmaf(wrow[k*WIG_LD+m], Fr[m*32+chh], val);
                atomicAdd(&orow[p], val);
            }
        }
    }
}

// ---------------------------------------------------------------- launch
extern "C" void kernel_launch(void* const* d_in, const int* in_sizes, int n_in,
                              void* d_out, int out_size, void* d_ws, size_t ws_size,
                              hipStream_t stream)
{
    const int*   species     = (const int*)d_in[0];
    const float* edge_embeds = (const float*)d_in[1];
    const int*   senders     = (const int*)d_in[2];
    const int*   receivers   = (const int*)d_in[3];
    const float* wigner      = (const float*)d_in[4];
    const float* embed_table = (const float*)d_in[5];
    const float* W0 = (const float*)d_in[6];
    const float* b0 = (const float*)d_in[7];
    const float* ln0s = (const float*)d_in[8];
    const float* ln0b = (const float*)d_in[9];
    const float* W1 = (const float*)d_in[10];
    const float* b1 = (const float*)d_in[11];
    const float* ln1s = (const float*)d_in[12];
    const float* ln1b = (const float*)d_in[13];
    const float* W2 = (const float*)d_in[14];
    const float* b2 = (const float*)d_in[15];
    float* out = (float*)d_out;

    const int n_nodes = in_sizes[0];
    const int n_edges = in_sizes[2];

    const size_t wpBytes   = WPBYTES;
    const size_t fBytes    = (size_t)n_edges * NOUT * sizeof(float);
    const size_t offBytes  = (size_t)(n_nodes + 1) * sizeof(int);
    const size_t curBytes  = (size_t)n_nodes * sizeof(int);
    const size_t listBytes = (size_t)n_edges * sizeof(int);
    const size_t need = wpBytes + fBytes + offBytes + curBytes + listBytes + 64;

    if (ws_size < need || n_nodes > SCAN_T * SCAN_CH || n_edges <= 0) {
        hipMemsetAsync(out, 0, (size_t)out_size * sizeof(float), stream);
        const int nblocks = (n_edges + EB - 1) / EB;
        hipLaunchKernelGGL(edge_fused_kernel, dim3(nblocks), dim3(256), 0, stream,
                           species, edge_embeds, senders, receivers, wigner, embed_table,
                           W0, b0, ln0s, ln0b, W1, b1, ln1s, ln1b, W2, b2, out, n_edges);
        return;
    }

    char* ws = (char*)d_ws;
    unsigned short* Wp = (unsigned short*)ws;
    float* F       = (float*)(ws + wpBytes);
    int*   offsets = (int*)(ws + wpBytes + fBytes);
    int*   cursor  = (int*)(ws + wpBytes + fBytes + offBytes);
    int*   elist   = (int*)(ws + wpBytes + fBytes + offBytes + curBytes);

    const int egrid = (n_edges + 255) / 256;

    // weight repack (tiny; L2-resident afterwards)
    hipLaunchKernelGGL(repack_w, dim3(336), dim3(256), 0, stream, W0, W1, W2, Wp);

    // CSR build (scan also initializes cursor)
    hipMemsetAsync(cursor, 0, curBytes, stream);
    hipLaunchKernelGGL(hist_kernel, dim3(egrid), dim3(256), 0, stream,
                       receivers, cursor, n_edges);
    hipLaunchKernelGGL(scan_kernel, dim3(1), dim3(SCAN_T), 0, stream,
                       cursor, offsets, cursor, n_nodes);
    hipLaunchKernelGGL(scatter_kernel, dim3(egrid), dim3(256), 0, stream,
                       receivers, cursor, elist, n_edges);

    // MLP (MFMA, MB=64, single-term weights, A-frag reuse 1x4/1x5) -> F
    const int mblocks = (n_edges + MB - 1) / MB;
    hipLaunchKernelGGL(mlp_mfma, dim3(mblocks), dim3(MTHREADS), 0, stream,
                       species, edge_embeds, senders, receivers, embed_table,
                       (const char*)Wp, b0, ln0s, ln0b, b1, ln1s, ln1b, b2, F, n_edges);

    // gather-aggregate -> out (256 thr/node)
    hipLaunchKernelGGL(agg_kernel, dim3(n_nodes), dim3(256), 0, stream,
                       wigner, F, offsets, elist, out);
}

// Round 13
// 479.329 us; speedup vs baseline: 1.4671x; 1.1058x over previous
//
#include <hip/hip_runtime.h>
#include <hip/hip_bf16.h>
#include <cstddef>

// EdgeDegreeEmbedding, round 12 = round-9 mlp (proven best, 502us) +
//  (1) schedule packing: {hist || repack} fused in one dispatch,
//      {scatter || mlp} fused in one dispatch (dependence graph allows it;
//      role branch on blockIdx, scatter blocks first). Removes ~45us of
//      serial CSR time.
//  (2) F stored/read as bf16: -204MB of ws traffic (~30us). absmax budget:
//      one extra 2^-9 rel rounding on F -> ~0.05 vs 0.1456 threshold.
// agg = r9 256-thr version (bf16 F reads). Fallback: round-0 kernel.

#define MB 64
#define MTHREADS 512
#define DIN 384
#define HDIM 128
#define NOUT 160
#define NKF 25
#define WIG_LD 19
#define WIG_ROW 475

#define WP1OFF 98304     // bytes: W0 pack = 12kt*8nt*1024
#define WP2OFF 131072    // + W1 pack 4*8*1024 = 32768
#define WPBYTES 172032   // + W2 pack 4*10*1024 = 40960

// LDS layout (bytes)
#define XS_B   784       // Xb row stride: (384+8) bf16
#define FS_B   528       // Hf row stride: 132 f32
#define HS_B   272       // Hb row stride: (128+8) bf16
#define REG0   0         // Xb (64*784=50176) / Hf (64*528=33792)
#define REG1   50176     // Hb (64*272=17408)
#define METAS  67584     // sS[64]
#define METAR  67840     // rS[64]
#define LDSSZ  68096

typedef __attribute__((ext_vector_type(8))) short short8;
typedef __attribute__((ext_vector_type(4))) float f32x4;

struct BF4 { __hip_bfloat162 a, b; };   // 8 B = 4 bf16

__device__ __forceinline__ unsigned short f2bf(float f)
{
    union { float f; unsigned u; } x; x.f = f;
    unsigned r = x.u + 0x7fffu + ((x.u >> 16) & 1u);
    return (unsigned short)(r >> 16);
}

// ---------------------------------------------------------------- K1: hist || repack
// B-frag block (1024 B) = one (kt, nt): 64 lanes x 8 bf16.
// lane l holds B[kt*32 + 8*(l>>4)+i][nt*16 + (l&15)]. Single term (RN bf16).
__global__ void pre_kernel(const int* __restrict__ recv, int* __restrict__ cnt,
                           int n_edges, int hgrid,
                           const float* __restrict__ W0, const float* __restrict__ W1,
                           const float* __restrict__ W2, unsigned short* __restrict__ Wp)
{
    const int bid = blockIdx.x;
    if (bid < hgrid) {                      // hist role
        const int e = bid * 256 + threadIdx.x;
        if (e < n_edges) atomicAdd(&cnt[recv[e]], 1);
        return;
    }
    // repack role
    const int id = (bid - hgrid) * 256 + threadIdx.x;
    const float* W; int k, n, NT, N; size_t base;  // base in ushort units
    if (id < 49152)      { W = W0; k = id >> 7;  n = id & 127;  NT = 8;  N = 128; base = 0; }
    else if (id < 65536) { int r = id - 49152; W = W1; k = r >> 7; n = r & 127; NT = 8; N = 128; base = 49152; }
    else if (id < 86016) { int r = id - 65536; W = W2; k = r / 160; n = r - 160 * k; NT = 10; N = 160; base = 65536; }
    else return;
    const float w = W[(size_t)k * N + n];
    const int kt = k >> 5, kk = k & 31;
    const int l = ((kk >> 3) << 4) | (n & 15);
    const int i = kk & 7;
    const int nt = n >> 4;
    Wp[base + (size_t)(kt * NT + nt) * 512 + l * 8 + i] = f2bf(w);
}

// ---------------------------------------------------------------- GEMM core (r9)
// 4 M-tiles (64 rows) per wave, one N-tile nt. Fully unrolled; B[kt+1]
// prefetched into registers before kt's MFMAs (hides L2 latency).
template<int NT, int KT>
__device__ __forceinline__ void gemm_tiles4(const char* __restrict__ ldsA, int astride,
                                            const char* __restrict__ wp,
                                            int nt, int lane, f32x4 acc[4])
{
    const int lr = lane & 15, lk = lane >> 4;
    short8 bcur = *(const short8*)(wp + (size_t)nt * 1024 + lane * 16);
#pragma unroll
    for (int kt = 0; kt < KT; ++kt) {
        short8 bnxt = bcur;
        if (kt + 1 < KT)
            bnxt = *(const short8*)(wp + (size_t)((kt + 1) * NT + nt) * 1024 + lane * 16);
        short8 a[4];
#pragma unroll
        for (int mt = 0; mt < 4; ++mt)
            a[mt] = *(const short8*)(ldsA + (mt * 16 + lr) * astride + kt * 64 + lk * 16);
#pragma unroll
        for (int mt = 0; mt < 4; ++mt)
            acc[mt] = __builtin_amdgcn_mfma_f32_16x16x32_bf16(a[mt], bcur, acc[mt], 0, 0, 0);
        bcur = bnxt;
    }
}

__device__ __forceinline__ void dump_acc4(char* Hf, int nt, int lane, const f32x4 acc[4],
                                          const float bias)
{
    const int lr = lane & 15, lk = lane >> 4;
#pragma unroll
    for (int mt = 0; mt < 4; ++mt)
#pragma unroll
        for (int i = 0; i < 4; ++i)
            *(float*)(Hf + (mt * 16 + lk * 4 + i) * FS_B + (nt * 16 + lr) * 4) = acc[mt][i] + bias;
}

// LN + silu: read f32 (FS_B), write packed bf16 (HS_B). 512 thr, 64 rows,
// 8 threads/row x 16 channels.  (r9 verbatim)
__device__ __forceinline__ void ln_silu_bf(const char* Hf, char* Hb,
                                           const float* __restrict__ s,
                                           const float* __restrict__ b, int t)
{
    const int j = t & 7;
    const int r = t >> 3;
    float v[16];
    float sum = 0.f, sq = 0.f;
#pragma unroll
    for (int q4 = 0; q4 < 4; ++q4) {
        const float4 x4 = *(const float4*)(Hf + r * FS_B + (j * 16 + q4 * 4) * 4);
        v[q4 * 4 + 0] = x4.x; v[q4 * 4 + 1] = x4.y;
        v[q4 * 4 + 2] = x4.z; v[q4 * 4 + 3] = x4.w;
    }
#pragma unroll
    for (int q = 0; q < 16; ++q) { sum += v[q]; sq = fmaf(v[q], v[q], sq); }
#pragma unroll
    for (int m = 1; m < 8; m <<= 1) {
        sum += __shfl_xor(sum, m, 64);
        sq  += __shfl_xor(sq,  m, 64);
    }
    const float mu = sum * (1.f / 128.f);
    const float var = sq * (1.f / 128.f) - mu * mu;
    const float rstd = rsqrtf(var + 1e-6f);
#pragma unroll
    for (int q = 0; q < 16; q += 2) {
        const int c0 = j * 16 + q;
        float y0 = (v[q] - mu) * rstd * s[c0] + b[c0];
        float y1 = (v[q + 1] - mu) * rstd * s[c0 + 1] + b[c0 + 1];
        y0 = y0 / (1.f + __expf(-y0));
        y1 = y1 / (1.f + __expf(-y1));
        *(__hip_bfloat162*)(Hb + r * HS_B + c0 * 2) =
            __float22bfloat162_rn(make_float2(y0, y1));
    }
}

// ---------------------------------------------------------------- K3: scatter || MLP
__global__ __launch_bounds__(MTHREADS, 2)
void mlp_mfma(
    const int* __restrict__ species,
    const float* __restrict__ edge_embeds,
    const int* __restrict__ senders,
    const int* __restrict__ receivers,
    const float* __restrict__ embed_table,
    const char* __restrict__ Wp,
    const float* __restrict__ b0, const float* __restrict__ ln0s, const float* __restrict__ ln0b,
    const float* __restrict__ b1, const float* __restrict__ ln1s, const float* __restrict__ ln1b,
    const float* __restrict__ b2,
    __hip_bfloat16* __restrict__ F,       // [E,160] bf16
    int* __restrict__ cursor, int* __restrict__ elist, int sgrid,
    int n_edges)
{
    __shared__ alignas(16) char lds[LDSSZ];

    const int bid = blockIdx.x;
    const int t = threadIdx.x;

    if (bid < sgrid) {                      // scatter role (512 edges/block)
        const int e = bid * MTHREADS + t;
        if (e < n_edges) {
            const int p = atomicAdd(&cursor[receivers[e]], 1);
            elist[p] = e;
        }
        return;
    }

    int* sS = (int*)(lds + METAS);
    int* rS = (int*)(lds + METAR);

    const int e0 = (bid - sgrid) * MB;
    const int w = t >> 6;
    const int lane = t & 63;
    const int lr = lane & 15, lk = lane >> 4;

    if (t < MB) {
        const int e = e0 + t;
        int s = 0, r = 0;
        if (e < n_edges) { s = senders[e]; r = receivers[e]; }
        sS[t] = species[s];
        rS[t] = species[r];
    }
    __syncthreads();

    // ---- stage X -> bf16 LDS (8 threads/row, 4-col chunks, stride 32) ----
    {
        const int row = t >> 3;            // 0..63
        const int e = e0 + row;
        const bool ev = e < n_edges;
        const int ss = sS[row], rr = rS[row];
        char* xrow = lds + REG0 + row * XS_B;
        const int c0 = (t & 7) * 4;
#pragma unroll
        for (int jj = 0; jj < 12; ++jj) {
            const int col = c0 + 32 * jj;   // jj<4: edge; jj<8: sender; else recv
            float4 v = make_float4(0.f, 0.f, 0.f, 0.f);
            if (ev) {
                if (jj < 4)
                    v = *(const float4*)(edge_embeds + (size_t)e * 128 + col);
                else if (jj < 8)
                    v = *(const float4*)(embed_table + (size_t)ss * 256 + (col - 128));
                else
                    v = *(const float4*)(embed_table + (size_t)rr * 256 + 128 + (col - 256));
            }
            BF4 pk;
            pk.a = __float22bfloat162_rn(make_float2(v.x, v.y));
            pk.b = __float22bfloat162_rn(make_float2(v.z, v.w));
            *(BF4*)(xrow + col * 2) = pk;
        }
    }
    __syncthreads();

    const char* wp0 = Wp;
    const char* wp1 = Wp + WP1OFF;
    const char* wp2 = Wp + WP2OFF;

    f32x4 acc[4];

    // ---- GEMM1: X[64,384] @ W0 -> H0 (wave w owns nt = w) ----
#pragma unroll
    for (int mt = 0; mt < 4; ++mt) acc[mt] = (f32x4){0.f, 0.f, 0.f, 0.f};
    gemm_tiles4<8, 12>(lds + REG0, XS_B, wp0, w, lane, acc);
    __syncthreads();                       // Xb dead before Hf overwrite
    dump_acc4(lds + REG0, w, lane, acc, b0[w * 16 + lr]);
    __syncthreads();
    ln_silu_bf(lds + REG0, lds + REG1, ln0s, ln0b, t);   // Hf -> Hb
    __syncthreads();

    // ---- GEMM2: H0[64,128] @ W1 -> H1 ----
#pragma unroll
    for (int mt = 0; mt < 4; ++mt) acc[mt] = (f32x4){0.f, 0.f, 0.f, 0.f};
    gemm_tiles4<8, 4>(lds + REG1, HS_B, wp1, w, lane, acc);
    // no barrier: dump writes REG0 (Hf) whose readers finished before the
    // previous barrier; GEMM2 read REG1 only.
    dump_acc4(lds + REG0, w, lane, acc, b1[w * 16 + lr]);
    __syncthreads();
    ln_silu_bf(lds + REG0, lds + REG1, ln1s, ln1b, t);   // Hf -> Hb
    __syncthreads();

    // ---- GEMM3: H1[64,128] @ W2 -> F (x0.2, bf16), nt = w, w+8 (<10) ----
#pragma unroll
    for (int p = 0; p < 2; ++p) {
        const int nt = w + 8 * p;
        if (nt >= 10) break;
#pragma unroll
        for (int mt = 0; mt < 4; ++mt) acc[mt] = (f32x4){0.f, 0.f, 0.f, 0.f};
        gemm_tiles4<10, 4>(lds + REG1, HS_B, wp2, nt, lane, acc);
        const float bb = b2[nt * 16 + lr];
#pragma unroll
        for (int mt = 0; mt < 4; ++mt)
#pragma unroll
            for (int i = 0; i < 4; ++i) {
                const int e = e0 + mt * 16 + lk * 4 + i;
                if (e < n_edges) {
                    union { unsigned short u; __hip_bfloat16 h; } cv;
                    cv.u = f2bf((acc[mt][i] + bb) * 0.2f);
                    F[(size_t)e * NOUT + nt * 16 + lr] = cv.h;
                }
            }
    }
}

// ---------------------------------------------------------------- scan
#define SCAN_T 1024
#define SCAN_CH 20
__global__ __launch_bounds__(SCAN_T)
void scan_kernel(const int* __restrict__ cnt, int* __restrict__ offsets,
                 int* __restrict__ cursor, int n_nodes)
{
    __shared__ int waveSum[SCAN_T / 64];
    const int t = threadIdx.x;
    const int base = t * SCAN_CH;
    int local[SCAN_CH];
    int s = 0;
#pragma unroll
    for (int j = 0; j < SCAN_CH; ++j) {
        const int v = (base + j < n_nodes) ? cnt[base + j] : 0;
        local[j] = s;
        s += v;
    }
    const int lane = t & 63;
    int incl = s;
#pragma unroll
    for (int d = 1; d < 64; d <<= 1) {
        const int u = __shfl_up(incl, d, 64);
        if (lane >= d) incl += u;
    }
    if (lane == 63) waveSum[t >> 6] = incl;
    __syncthreads();
    if (t < SCAN_T / 64) {
        const int v = waveSum[t];
        int incl2 = v;
#pragma unroll
        for (int d = 1; d < SCAN_T / 64; d <<= 1) {
            const int u = __shfl_up(incl2, d, 64);
            if (lane >= d) incl2 += u;
        }
        waveSum[t] = incl2 - v;
    }
    __syncthreads();
    const int threadExcl = waveSum[t >> 6] + (incl - s);
#pragma unroll
    for (int j = 0; j < SCAN_CH; ++j)
        if (base + j < n_nodes) {
            const int o = threadExcl + local[j];
            offsets[base + j] = o;
            cursor[base + j] = o;
        }
    if (t == SCAN_T - 1) offsets[n_nodes] = threadExcl + s;
}

// ---------------------------------------------------------------- aggregation
// 256 threads per node: ch=t&31, k0=t>>5 covers k0, k0+8, k0+16 (+24 for
// t<32); F (bf16) reg-prefetched; wigner LDS double-buffered.
__global__ __launch_bounds__(256)
void agg_kernel(const float* __restrict__ wigner, const __hip_bfloat16* __restrict__ F,
                const int* __restrict__ offsets, const int* __restrict__ elist,
                float* __restrict__ out)
{
    const int n = blockIdx.x;
    const int t = threadIdx.x;
    __shared__ float wigS[2][128];

    const int beg = offsets[n];
    const int end = offsets[n + 1];

    const int ch = t & 31;
    const int k0 = t >> 5;
    float a0 = 0.f, a1 = 0.f, a2 = 0.f, a3 = 0.f;

    float f[5];
    if (beg < end) {
        const int e = elist[beg];
        if (t < 125) wigS[0][t] = wigner[(size_t)e * WIG_ROW + (t / 5) * WIG_LD + (t % 5)];
        const __hip_bfloat16* Fp = F + (size_t)e * NOUT + ch;
#pragma unroll
        for (int m = 0; m < 5; ++m) f[m] = __bfloat162float(Fp[m * 32]);
    }

    int buf = 0;
    for (int i = beg; i < end; ++i) {
        __syncthreads();
        float fc[5];
#pragma unroll
        for (int m = 0; m < 5; ++m) fc[m] = f[m];
        if (i + 1 < end) {
            const int e = elist[i + 1];
            if (t < 125) wigS[buf ^ 1][t] = wigner[(size_t)e * WIG_ROW + (t / 5) * WIG_LD + (t % 5)];
            const __hip_bfloat16* Fp = F + (size_t)e * NOUT + ch;
#pragma unroll
            for (int m = 0; m < 5; ++m) f[m] = __bfloat162float(Fp[m * 32]);
        }
        const float* wp = &wigS[buf][0];
        { const float* wq = wp + k0 * 5;        a0 += wq[0]*fc[0] + wq[1]*fc[1] + wq[2]*fc[2] + wq[3]*fc[3] + wq[4]*fc[4]; }
        { const float* wq = wp + (k0 + 8) * 5;  a1 += wq[0]*fc[0] + wq[1]*fc[1] + wq[2]*fc[2] + wq[3]*fc[3] + wq[4]*fc[4]; }
        { const float* wq = wp + (k0 + 16) * 5; a2 += wq[0]*fc[0] + wq[1]*fc[1] + wq[2]*fc[2] + wq[3]*fc[3] + wq[4]*fc[4]; }
        if (t < 32) { const float* wq = wp + 120; a3 += wq[0]*fc[0] + wq[1]*fc[1] + wq[2]*fc[2] + wq[3]*fc[3] + wq[4]*fc[4]; }
        buf ^= 1;
    }

    float* orow = out + (size_t)n * (NKF * 32);
    orow[t] = a0;
    orow[t + 256] = a1;
    orow[t + 512] = a2;
    if (t < 32) orow[t + 768] = a3;
}

// ---------------------------------------------------------------- fallback (round-0)
#define EB 32
__device__ __forceinline__ void ln_silu_f(float (*Bx)[HDIM], const float* __restrict__ s,
                                          const float* __restrict__ b, int t)
{
    const int r = t >> 3;
    const int j = t & 7;
    float v[16];
    float sum = 0.f, sq = 0.f;
#pragma unroll
    for (int q = 0; q < 16; ++q) { v[q] = Bx[r][j*16+q]; sum += v[q]; sq = fmaf(v[q], v[q], sq); }
#pragma unroll
    for (int m = 1; m < 8; m <<= 1) { sum += __shfl_xor(sum, m, 64); sq += __shfl_xor(sq, m, 64); }
    const float mu = sum * (1.f/HDIM);
    const float var = sq * (1.f/HDIM) - mu*mu;
    const float rstd = rsqrtf(var + 1e-6f);
#pragma unroll
    for (int q = 0; q < 16; ++q) {
        const int cc = j*16+q;
        const float y = (v[q]-mu)*rstd*s[cc]+b[cc];
        Bx[r][cc] = y / (1.f + __expf(-y));
    }
}

__global__ __launch_bounds__(256, 2)
void edge_fused_kernel(
    const int* __restrict__ species, const float* __restrict__ edge_embeds,
    const int* __restrict__ senders, const int* __restrict__ receivers,
    const float* __restrict__ wigner, const float* __restrict__ embed_table,
    const float* __restrict__ W0, const float* __restrict__ b0,
    const float* __restrict__ ln0s, const float* __restrict__ ln0b,
    const float* __restrict__ W1, const float* __restrict__ b1,
    const float* __restrict__ ln1s, const float* __restrict__ ln1b,
    const float* __restrict__ W2, const float* __restrict__ b2,
    float* __restrict__ out, int n_edges)
{
    __shared__ float A[EB][DIN];
    __shared__ float Bx[EB][HDIM];
    __shared__ int sSpec[EB], rSpec[EB], rNode[EB];
    const int t = threadIdx.x;
    const int e0 = blockIdx.x * EB;
    if (t < EB) {
        const int e = e0 + t;
        int s = 0, r = 0;
        if (e < n_edges) { s = senders[e]; r = receivers[e]; }
        sSpec[t] = species[s]; rSpec[t] = species[r]; rNode[t] = r;
    }
    __syncthreads();
    for (int idx = t; idx < EB * DIN; idx += 256) {
        const int r = idx / DIN;
        const int i = idx - r * DIN;
        const int e = e0 + r;
        float v = 0.f;
        if (e < n_edges) {
            if (i < HDIM) v = edge_embeds[(size_t)e * HDIM + i];
            else if (i < 2*HDIM) v = embed_table[(size_t)sSpec[r]*256 + (i-HDIM)];
            else v = embed_table[(size_t)rSpec[r]*256 + HDIM + (i-2*HDIM)];
        }
        A[r][i] = v;
    }
    __syncthreads();
    const int c = t & (HDIM-1);
    const int g = t >> 7;
    float acc[16];
#pragma unroll
    for (int q = 0; q < 16; ++q) acc[q] = 0.f;
    for (int it = 0; it < DIN/4; ++it) {
        const float wa = W0[(4*it+0)*HDIM+c], wb = W0[(4*it+1)*HDIM+c];
        const float wc = W0[(4*it+2)*HDIM+c], wd = W0[(4*it+3)*HDIM+c];
#pragma unroll
        for (int q = 0; q < 16; ++q) {
            const float4 x4 = *reinterpret_cast<const float4*>(&A[g*16+q][4*it]);
            acc[q] = fmaf(x4.x, wa, fmaf(x4.y, wb, fmaf(x4.z, wc, fmaf(x4.w, wd, acc[q]))));
        }
    }
    { const float bb = b0[c];
#pragma unroll
      for (int q = 0; q < 16; ++q) Bx[g*16+q][c] = acc[q] + bb; }
    __syncthreads(); ln_silu_f(Bx, ln0s, ln0b, t); __syncthreads();
#pragma unroll
    for (int q = 0; q < 16; ++q) acc[q] = 0.f;
    for (int it = 0; it < HDIM/4; ++it) {
        const float wa = W1[(4*it+0)*HDIM+c], wb = W1[(4*it+1)*HDIM+c];
        const float wc = W1[(4*it+2)*HDIM+c], wd = W1[(4*it+3)*HDIM+c];
#pragma unroll
        for (int q = 0; q < 16; ++q) {
            const float4 x4 = *reinterpret_cast<const float4*>(&Bx[g*16+q][4*it]);
            acc[q] = fmaf(x4.x, wa, fmaf(x4.y, wb, fmaf(x4.z, wc, fmaf(x4.w, wd, acc[q]))));
        }
    }
    __syncthreads();
    { const float bb = b1[c];
#pragma unroll
      for (int q = 0; q < 16; ++q) Bx[g*16+q][c] = acc[q] + bb; }
    __syncthreads(); ln_silu_f(Bx, ln1s, ln1b, t); __syncthreads();
    float* Ff = &A[0][0];
    {
        float a2[16];
#pragma unroll
        for (int q = 0; q < 16; ++q) a2[q] = 0.f;
        for (int it = 0; it < HDIM/4; ++it) {
            const float wa = W2[(4*it+0)*NOUT+c], wb = W2[(4*it+1)*NOUT+c];
            const float wc = W2[(4*it+2)*NOUT+c], wd = W2[(4*it+3)*NOUT+c];
#pragma unroll
            for (int q = 0; q < 16; ++q) {
                const float4 x4 = *reinterpret_cast<const float4*>(&Bx[g*16+q][4*it]);
                a2[q] = fmaf(x4.x, wa, fmaf(x4.y, wb, fmaf(x4.z, wc, fmaf(x4.w, wd, a2[q]))));
            }
        }
        const float bb = b2[c];
#pragma unroll
        for (int q = 0; q < 16; ++q) Ff[(g*16+q)*NOUT+c] = (a2[q]+bb)*0.2f;
    }
    {
        const int c2 = HDIM + (t & 31);
        const int g8 = t >> 5;
        float a2[4] = {0.f, 0.f, 0.f, 0.f};
        for (int it = 0; it < HDIM/4; ++it) {
            const float wa = W2[(4*it+0)*NOUT+c2], wb = W2[(4*it+1)*NOUT+c2];
            const float wc = W2[(4*it+2)*NOUT+c2], wd = W2[(4*it+3)*NOUT+c2];
#pragma unroll
            for (int q = 0; q < 4; ++q) {
                const float4 x4 = *reinterpret_cast<const float4*>(&Bx[g8*4+q][4*it]);
                a2[q] = fmaf(x4.x, wa, fmaf(x4.y, wb, fmaf(x4.z, wc, fmaf(x4.w, wd, a2[q]))));
            }
        }
        const float bb = b2[c2];
#pragma unroll
        for (int q = 0; q < 4; ++q) Ff[(g8*4+q)*NOUT+c2] = (a2[q]+bb)*0.2f;
    }
    __syncthreads();
    for (int r = 0; r < EB; ++r) {
        const int e = e0 + r;
        if (e >= n_edges) break;
        const float* wrow = wigner + (size_t)e * WIG_ROW;
        float* orow = out + (size_t)rNode[r] * (NKF*32);
        const float* Fr = Ff + r * NOUT;
#pragma unroll
        for (int jj = 0; jj < 4; ++jj) {
            const int p = t + 256*jj;
            if (p < NKF*32) {
                const int k = p >> 5, chh = p & 31;
                float val = 0.f;
#pragma unroll
                for (int m = 0; m < 5; ++m)
                    val = fmaf(wrow[k*WIG_LD+m], Fr[m*32+chh], val);
                atomicAdd(&orow[p], val);
            }
        }
    }
}

// ---------------------------------------------------------------- launch
extern "C" void kernel_launch(void* const* d_in, const int* in_sizes, int n_in,
                              void* d_out, int out_size, void* d_ws, size_t ws_size,
                              hipStream_t stream)
{
    const int*   species     = (const int*)d_in[0];
    const float* edge_embeds = (const float*)d_in[1];
    const int*   senders     = (const int*)d_in[2];
    const int*   receivers   = (const int*)d_in[3];
    const float* wigner      = (const float*)d_in[4];
    const float* embed_table = (const float*)d_in[5];
    const float* W0 = (const float*)d_in[6];
    const float* b0 = (const float*)d_in[7];
    const float* ln0s = (const float*)d_in[8];
    const float* ln0b = (const float*)d_in[9];
    const float* W1 = (const float*)d_in[10];
    const float* b1 = (const float*)d_in[11];
    const float* ln1s = (const float*)d_in[12];
    const float* ln1b = (const float*)d_in[13];
    const float* W2 = (const float*)d_in[14];
    const float* b2 = (const float*)d_in[15];
    float* out = (float*)d_out;

    const int n_nodes = in_sizes[0];
    const int n_edges = in_sizes[2];

    const size_t wpBytes   = WPBYTES;
    const size_t fBytes    = (size_t)n_edges * NOUT * sizeof(unsigned short);
    const size_t offBytes  = (size_t)(n_nodes + 1) * sizeof(int);
    const size_t curBytes  = (size_t)n_nodes * sizeof(int);
    const size_t listBytes = (size_t)n_edges * sizeof(int);
    const size_t need = wpBytes + fBytes + offBytes + curBytes + listBytes + 64;

    if (ws_size < need || n_nodes > SCAN_T * SCAN_CH || n_edges <= 0) {
        hipMemsetAsync(out, 0, (size_t)out_size * sizeof(float), stream);
        const int nblocks = (n_edges + EB - 1) / EB;
        hipLaunchKernelGGL(edge_fused_kernel, dim3(nblocks), dim3(256), 0, stream,
                           species, edge_embeds, senders, receivers, wigner, embed_table,
                           W0, b0, ln0s, ln0b, W1, b1, ln1s, ln1b, W2, b2, out, n_edges);
        return;
    }

    char* ws = (char*)d_ws;
    unsigned short* Wp = (unsigned short*)ws;
    __hip_bfloat16* F  = (__hip_bfloat16*)(ws + wpBytes);
    int*   offsets = (int*)(ws + wpBytes + fBytes);
    int*   cursor  = (int*)(ws + wpBytes + fBytes + offBytes);
    int*   elist   = (int*)(ws + wpBytes + fBytes + offBytes + curBytes);

    const int hgrid = (n_edges + 255) / 256;

    // K1: hist || repack  (independent; cnt lives in cursor buffer)
    hipMemsetAsync(cursor, 0, curBytes, stream);
    hipLaunchKernelGGL(pre_kernel, dim3(hgrid + 336), dim3(256), 0, stream,
                       receivers, cursor, n_edges, hgrid, W0, W1, W2, Wp);

    // K2: scan (writes offsets + re-inits cursor)
    hipLaunchKernelGGL(scan_kernel, dim3(1), dim3(SCAN_T), 0, stream,
                       cursor, offsets, cursor, n_nodes);

    // K3: scatter || MLP  (scatter blocks first; both deps satisfied)
    const int sgrid = (n_edges + MTHREADS - 1) / MTHREADS;
    const int mblocks = (n_edges + MB - 1) / MB;
    hipLaunchKernelGGL(mlp_mfma, dim3(sgrid + mblocks), dim3(MTHREADS), 0, stream,
                       species, edge_embeds, senders, receivers, embed_table,
                       (const char*)Wp, b0, ln0s, ln0b, b1, ln1s, ln1b, b2,
                       F, cursor, elist, sgrid, n_edges);

    // K4: gather-aggregate -> out (256 thr/node, bf16 F)
    hipLaunchKernelGGL(agg_kernel, dim3(n_nodes), dim3(256), 0, stream,
                       wigner, F, offsets, elist, out);
}